// Round 8
// baseline (763.882 us; speedup 1.0000x reference)
//
#include <hip/hip_runtime.h>

// Euclidean transformer layer, MI355X, round 8.
// k_edge: bf16 MFMA filter GEMMs; now writes per-edge alpha only (no scatter).
// NEW: CSR (counting sort by receiver) + gather-based aggregation fused into
// k_final — eliminates 29.4M device atomics (round-7 counters: WRITE_SIZE
// 112MB = atomic count x 4B, FETCH 172MB; k_edge stall-bound at 21% VALU).

#define NN 20000
#define NE 200000
#define FD 132
#define RB 32
#define EVD 15
#define TE 64      // edges per block (200000 = 3125 * 64, exact)
#define KPAD 200   // HT LDS k-stride in bf16
#define KG 192     // global W2T k-stride
#define NP 144     // padded n (132 -> 9 tiles of 16)
#define PNT 28     // nodes per block in k_proj
#define FNT 28     // nodes per block in k_final

typedef __attribute__((ext_vector_type(8))) short bf16x8;
typedef __attribute__((ext_vector_type(4))) float f32x4;

__device__ __forceinline__ float silu_f(float x) {
    return x / (1.0f + __expf(-x));
}
__device__ __forceinline__ unsigned short f2bf(float x) {
    union { float f; unsigned u; } v; v.f = x;
    unsigned r = v.u + 0x7FFF + ((v.u >> 16) & 1);   // RNE
    return (unsigned short)(r >> 16);
}

// ---------------- prep: weight reshape/convert (idempotent, every call) ------
__global__ __launch_bounds__(256) void k_prep(
    const float* __restrict__ Wq, const float* __restrict__ Wk, const float* __restrict__ Wv,
    const float* __restrict__ fiW1, const float* __restrict__ fiW2, const float* __restrict__ fiWe2,
    const float* __restrict__ feW1, const float* __restrict__ feW2, const float* __restrict__ feWe2,
    unsigned short* __restrict__ W1Tfi, unsigned short* __restrict__ W1Tfe,
    unsigned short* __restrict__ W2Tfi, unsigned short* __restrict__ W2Tfe,
    float* __restrict__ WqP, float* __restrict__ WkP, float* __restrict__ WvP)
{
    const int gid = blockIdx.x * 256 + threadIdx.x;
    const int gs  = gridDim.x * 256;
    for (int idx = gid; idx < NP * RB; idx += gs) {
        int n = idx / RB, k = idx - n * RB;
        W1Tfi[idx] = f2bf((n < FD) ? fiW1[k * FD + n] : 0.0f);
        W1Tfe[idx] = f2bf((n < FD) ? feW1[k * FD + n] : 0.0f);
    }
    for (int idx = gid; idx < NP * KG; idx += gs) {
        int n = idx / KG, k = idx - n * KG;
        float vi = 0.0f, ve = 0.0f;
        if (n < FD) {
            if (k < FD)       { vi = fiW2[k * FD + n];          ve = feW2[k * FD + n]; }
            else if (k < 165) { vi = fiWe2[(k - FD) * FD + n];  ve = feWe2[(k - FD) * FD + n]; }
        }
        W2Tfi[idx] = f2bf(vi);
        W2Tfe[idx] = f2bf(ve);
    }
    for (int idx = gid; idx < 4 * 33 * 36; idx += gs) {
        int H = idx / (33 * 36), rem = idx - H * (33 * 36);
        int i = rem / 36, jp = rem - i * 36;
        float q = 0.f, k = 0.f, v = 0.f;
        if (jp < 33) {
            q = Wq[H * 1089 + i * 33 + jp];
            k = Wk[H * 1089 + i * 33 + jp];
            v = Wv[H * 1089 + i * 33 + jp];
        }
        WqP[idx] = q; WkP[idx] = k; WvP[idx] = v;
    }
}

// ---------------- CSR build: counting sort by receiver -----------------------
__global__ __launch_bounds__(256) void k_hist(const int* __restrict__ rcv,
                                              int* __restrict__ cnt)
{
    int e = blockIdx.x * 256 + threadIdx.x;
    if (e < NE) atomicAdd(&cnt[rcv[e]], 1);
}

__global__ __launch_bounds__(256) void k_scan(int* __restrict__ cnt_cursor,
                                              int* __restrict__ roff)
{
    __shared__ int buf[256];
    __shared__ int carry_s;
    const int t = threadIdx.x;
    if (t == 0) carry_s = 0;
    __syncthreads();
    for (int base = 0; base < NN; base += 256) {
        int v = (base + t < NN) ? cnt_cursor[base + t] : 0;
        buf[t] = v;
        __syncthreads();
        for (int off = 1; off < 256; off <<= 1) {
            int add = (t >= off) ? buf[t - off] : 0;
            __syncthreads();
            buf[t] += add;
            __syncthreads();
        }
        int ex = carry_s + buf[t] - v;   // exclusive prefix
        if (base + t < NN) { roff[base + t] = ex; cnt_cursor[base + t] = ex; }
        __syncthreads();
        if (t == 0) carry_s += buf[255];
        __syncthreads();
    }
    if (t == 0) roff[NN] = carry_s;   // == NE
}

__global__ __launch_bounds__(256) void k_fill(const int* __restrict__ rcv,
                                              int* __restrict__ cursor,
                                              int* __restrict__ eid)
{
    int e = blockIdx.x * 256 + threadIdx.x;
    if (e < NE) {
        int p = atomicAdd(&cursor[rcv[e]], 1);
        eid[p] = e;
    }
}

// ---------------- node projections: LDS weights + 4x4 register tile ----------
__device__ __forceinline__ void proj_inv_pass(
    const float* __restrict__ wb, const float (*__restrict__ xT)[PNT],
    float* __restrict__ outp, int t, int n0)
{
    const int q = t % 36, g = t / 36;
    if (g >= 7) return;
    const int H = q / 9, jb = (q - H * 9) * 4, nb = g * 4;
    const int fb = H * 33;
    float acc[4][4] = {};
    for (int i = 0; i < 33; ++i) {
        const float4 w = *(const float4*)&wb[(fb + i) * 36 + jb];
        const float4 x = *(const float4*)&xT[fb + i][nb];
        const float xs[4] = {x.x, x.y, x.z, x.w};
        const float ws[4] = {w.x, w.y, w.z, w.w};
        #pragma unroll
        for (int r = 0; r < 4; ++r)
            #pragma unroll
            for (int c = 0; c < 4; ++c)
                acc[r][c] = fmaf(ws[c], xs[r], acc[r][c]);
    }
    #pragma unroll
    for (int c = 0; c < 4; ++c) {
        int jj = jb + c;
        if (jj >= 33) break;
        int j = H * 33 + jj;
        #pragma unroll
        for (int r = 0; r < 4; ++r) {
            int n = n0 + nb + r;
            if (n < NN) outp[n * FD + j] = acc[r][c];
        }
    }
}

__device__ __forceinline__ void proj_ev_pass(
    const float* __restrict__ wb, const float (*__restrict__ xT)[PNT],
    float* __restrict__ outp, int t, int n0)
{
    const int q = t % 33, g = t / 33;
    if (g >= 7) return;
    const int H = q / 11, jb = (q - H * 11) * 4, nb = g * 4;
    const int fb = H * 44;
    float acc[4][4] = {};
    for (int i = 0; i < 44; ++i) {
        const float4 w = *(const float4*)&wb[(fb + i) * 44 + jb];
        const float4 x = *(const float4*)&xT[fb + i][nb];
        const float xs[4] = {x.x, x.y, x.z, x.w};
        const float ws[4] = {w.x, w.y, w.z, w.w};
        #pragma unroll
        for (int r = 0; r < 4; ++r)
            #pragma unroll
            for (int c = 0; c < 4; ++c)
                acc[r][c] = fmaf(ws[c], xs[r], acc[r][c]);
    }
    #pragma unroll
    for (int c = 0; c < 4; ++c) {
        int j = fb + jb + c;
        #pragma unroll
        for (int r = 0; r < 4; ++r) {
            int n = n0 + nb + r;
            if (n < NN) outp[n * FD + j] = acc[r][c];
        }
    }
}

__global__ __launch_bounds__(256) void k_proj(
    const float* __restrict__ xin,
    const float* __restrict__ WqP, const float* __restrict__ WkP, const float* __restrict__ WvP,
    const float* __restrict__ Wqe, const float* __restrict__ Wke,
    float* __restrict__ qinv, float* __restrict__ kinv, float* __restrict__ vinv,
    float* __restrict__ qev, float* __restrict__ kev)
{
    __shared__ __align__(16) float xT[FD][PNT];
    __shared__ __align__(16) float wb[5808];
    const int t = threadIdx.x;
    const int n0 = blockIdx.x * PNT;

    for (int idx = t; idx < PNT * FD; idx += 256) {
        int nl = idx / FD, j = idx - nl * FD;
        int n = n0 + nl;
        xT[j][nl] = (n < NN) ? xin[n * FD + j] : 0.0f;
    }
    for (int idx = t; idx < 4752; idx += 256) wb[idx] = WqP[idx];
    __syncthreads();
    proj_inv_pass(wb, xT, qinv, t, n0);
    __syncthreads();
    for (int idx = t; idx < 4752; idx += 256) wb[idx] = WkP[idx];
    __syncthreads();
    proj_inv_pass(wb, xT, kinv, t, n0);
    __syncthreads();
    for (int idx = t; idx < 4752; idx += 256) wb[idx] = WvP[idx];
    __syncthreads();
    proj_inv_pass(wb, xT, vinv, t, n0);
    __syncthreads();
    for (int idx = t; idx < 5808; idx += 256) wb[idx] = Wqe[idx];
    __syncthreads();
    proj_ev_pass(wb, xT, qev, t, n0);
    __syncthreads();
    for (int idx = t; idx < 5808; idx += 256) wb[idx] = Wke[idx];
    __syncthreads();
    proj_ev_pass(wb, xT, kev, t, n0);
}

// ---------------- per-edge SO(3) invariants of ev-diff ------------------------
__global__ __launch_bounds__(256) void k_evi(
    const float* __restrict__ ev, const int* __restrict__ snd,
    const int* __restrict__ rcv, float* __restrict__ evi)
{
    int e = blockIdx.x * 256 + threadIdx.x;
    if (e >= NE) return;
    int s = snd[e], r = rcv[e];
    const float* ps = &ev[s * EVD];
    const float* pr = &ev[r * EVD];
    float s0 = 0.f, s1 = 0.f, s2 = 0.f;
    #pragma unroll
    for (int m = 0; m < 3; ++m)  { float d = ps[m] - pr[m]; s0 = fmaf(d, d, s0); }
    #pragma unroll
    for (int m = 3; m < 8; ++m)  { float d = ps[m] - pr[m]; s1 = fmaf(d, d, s1); }
    #pragma unroll
    for (int m = 8; m < 15; ++m) { float d = ps[m] - pr[m]; s2 = fmaf(d, d, s2); }
    evi[e * 3 + 0] = s0; evi[e * 3 + 1] = s1; evi[e * 3 + 2] = s2;
}

// ---------------- fused edge kernel: MFMA filter + attention -> alpha --------
// PATH 0: inv (4 heads x 33), PATH 1: ev (3 heads x 44). Writes alpha only;
// aggregation happens gather-side in k_final via CSR.
template<int PATH>
__global__ __launch_bounds__(256, 4) void k_edge(
    const float* __restrict__ rbf, const float* __restrict__ evi,
    const int* __restrict__ snd, const int* __restrict__ rcv,
    const float* __restrict__ cut,
    const unsigned short* __restrict__ W1T,  // [144][32] bf16
    const float* __restrict__ b1,
    const unsigned short* __restrict__ W2T,  // [144][192] bf16
    const float* __restrict__ b2,
    const float* __restrict__ We1, const float* __restrict__ be1,
    const float* __restrict__ be2,
    const float* __restrict__ qt, const float* __restrict__ kt,
    float* __restrict__ aout)
{
    // lds_buf: HT [64][200] bf16 (25.6KB) then aliased FW [64][132] f32 (33.8KB)
    __shared__ __align__(16) char lds_buf[TE * FD * 4];
    __shared__ float evl[TE * 3];
    __shared__ int   sl[TE];
    __shared__ int   rl[TE];
    __shared__ float cl[TE];

    typedef unsigned short (*HTp)[KPAD];
    HTp HT   = (HTp)lds_buf;
    float* FW = (float*)lds_buf;

    const int t    = threadIdx.x;
    const int wv   = t >> 6;
    const int ln   = t & 63;
    const int lrow = ln & 15;
    const int kseg = ln >> 4;
    const int e0   = blockIdx.x * TE;

    if (t < TE) {
        sl[t] = snd[e0 + t];
        rl[t] = rcv[e0 + t];
        cl[t] = cut[e0 + t];
    }
    for (int idx = t; idx < TE * 3; idx += 256) evl[idx] = evi[e0 * 3 + idx];
    __syncthreads();

    // ---- H-GEMM: h = silu(rbf @ W1 + b1) ----
    {
        const int erow = e0 + 16 * wv + lrow;
        const float4 ra = *(const float4*)&rbf[erow * RB + kseg * 8];
        const float4 rb = *(const float4*)&rbf[erow * RB + kseg * 8 + 4];
        bf16x8 afrag;
        afrag[0] = (short)f2bf(ra.x); afrag[1] = (short)f2bf(ra.y);
        afrag[2] = (short)f2bf(ra.z); afrag[3] = (short)f2bf(ra.w);
        afrag[4] = (short)f2bf(rb.x); afrag[5] = (short)f2bf(rb.y);
        afrag[6] = (short)f2bf(rb.z); afrag[7] = (short)f2bf(rb.w);
        #pragma unroll
        for (int nt = 0; nt < 9; ++nt) {
            const int ncol = nt * 16 + lrow;
            bf16x8 bfrag = *(const bf16x8*)&W1T[ncol * RB + kseg * 8];
            f32x4 acc = {0.f, 0.f, 0.f, 0.f};
            acc = __builtin_amdgcn_mfma_f32_16x16x32_bf16(afrag, bfrag, acc, 0, 0, 0);
            if (ncol < FD) {
                const float bias = b1[ncol];
                #pragma unroll
                for (int r = 0; r < 4; ++r)
                    HT[16 * wv + kseg * 4 + r][ncol] = f2bf(silu_f(acc[r] + bias));
            }
        }
    }
    // g rows 132..164: silu(evi @ We1 + be1)
    for (int idx = t; idx < TE * 33; idx += 256) {
        int e = idx / 33, ii = idx - e * 33;
        float a = be1[ii];
        a = fmaf(evl[e * 3 + 0], We1[ii], a);
        a = fmaf(evl[e * 3 + 1], We1[33 + ii], a);
        a = fmaf(evl[e * 3 + 2], We1[66 + ii], a);
        HT[e][FD + ii] = f2bf(silu_f(a));
    }
    // zero-pad k 165..199
    for (int idx = t; idx < TE * (KPAD - 165); idx += 256) {
        int e = idx / (KPAD - 165), kk = idx - e * (KPAD - 165);
        HT[e][165 + kk] = 0;
    }
    __syncthreads();

    // ---- main GEMM: fw[64][132] = Hext[64][165] @ Wcat[165][132] ----
    f32x4 acc[9];
    #pragma unroll
    for (int nt = 0; nt < 9; ++nt) acc[nt] = (f32x4){0.f, 0.f, 0.f, 0.f};
    {
        const unsigned short* hrow = &HT[16 * wv + lrow][0];
        #pragma unroll
        for (int kt = 0; kt < 6; ++kt) {
            bf16x8 afrag = *(const bf16x8*)&hrow[kt * 32 + kseg * 8];
            #pragma unroll
            for (int nt = 0; nt < 9; ++nt) {
                bf16x8 bfrag = *(const bf16x8*)&W2T[(nt * 16 + lrow) * KG + kt * 32 + kseg * 8];
                acc[nt] = __builtin_amdgcn_mfma_f32_16x16x32_bf16(afrag, bfrag, acc[nt], 0, 0, 0);
            }
        }
    }
    __syncthreads();   // HT dead; safe to overwrite as FW

    #pragma unroll
    for (int nt = 0; nt < 9; ++nt) {
        const int ncol = nt * 16 + lrow;
        if (ncol < FD) {
            const float bias = b2[ncol] + be2[ncol];
            #pragma unroll
            for (int r = 0; r < 4; ++r)
                FW[(16 * wv + kseg * 4 + r) * FD + ncol] = acc[nt][r] + bias;
        }
    }
    __syncthreads();

    // ---- qk products in place: FW[e][j] *= q[rcv][j] * k[snd][j] ----
    for (int idx = t; idx < TE * FD; idx += 256) {
        int e = idx / FD, j = idx - e * FD;
        FW[idx] *= qt[rl[e] * FD + j] * kt[sl[e] * FD + j];
    }
    __syncthreads();

    // ---- per-(edge,head) sums -> global alpha (cutoff & 1/sqrt(D) folded) ----
    if (PATH == 0) {
        int e = t >> 2, H = t & 3;   // 256 threads = 64 edges x 4 heads, exact
        const float* fp = &FW[e * FD + H * 33];
        float a = 0.0f;
        #pragma unroll
        for (int j = 0; j < 33; ++j) a += fp[j];
        aout[(e0 + e) * 4 + H] = a * cl[e] * 0.17407765595569785f;
    } else {
        if (t < TE * 3) {
            int e = t / 3, H = t - e * 3;
            const float* fp = &FW[e * FD + H * 44];
            float a = 0.0f;
            #pragma unroll
            for (int j = 0; j < 44; ++j) a += fp[j];
            aout[(e0 + e) * 4 + H] = a * cl[e] * 0.15075567228888181f;
        }
    }
}

// ---------------- final node update: CSR gather-aggregate + Wint GEMM --------
__global__ __launch_bounds__(256) void k_final(
    const float* __restrict__ xin, const float* __restrict__ evf,
    const float* __restrict__ vt, const float* __restrict__ sh,
    const float* __restrict__ alphaI, const float* __restrict__ alphaE,
    const int* __restrict__ roff, const int* __restrict__ eid,
    const int* __restrict__ snd,
    const float* __restrict__ Wint, const float* __restrict__ bint,
    float* __restrict__ out)
{
    __shared__ __align__(16) float catT[136][FNT];
    __shared__ __align__(16) float wb[45 * 136];
    __shared__ float aev[FNT][16];
    __shared__ float tacc[FNT][4];
    const int t = threadIdx.x;
    const int n0 = blockIdx.x * FNT;
    const int wv = t >> 6, ln = t & 63;

    // ---- aggregation: one wave per node, registers accumulate ----
    const int h0 = ln / 33;            // head of col ln       (0..1)
    const int h1 = (64 + ln) / 33;     // head of col 64+ln    (1..3)
    const int hm = (ln < 3) ? 0 : ((ln < 8) ? 1 : 2);
    for (int nl = wv; nl < FNT; nl += 4) {
        const int n = n0 + nl;
        float a0 = 0.f, a1 = 0.f, a2 = 0.f, dv = 0.f;
        if (n < NN) {
            const int pend = roff[n + 1];
            for (int p = roff[n]; p < pend; ++p) {
                const int e = eid[p];
                const int s = snd[e];
                const float* vrow = vt + s * FD;
                a0 = fmaf(alphaI[e * 4 + h0], vrow[ln], a0);
                a1 = fmaf(alphaI[e * 4 + h1], vrow[64 + ln], a1);
                if (ln < 4)  a2 = fmaf(alphaI[e * 4 + 3], vrow[128 + ln], a2);
                if (ln < 15) dv = fmaf(alphaE[e * 4 + hm], sh[e * EVD + ln], dv);
            }
            catT[ln][nl]      = xin[n * FD + ln]      + a0;
            catT[64 + ln][nl] = xin[n * FD + 64 + ln] + a1;
            if (ln < 4)  catT[128 + ln][nl] = xin[n * FD + 128 + ln] + a2;
            if (ln < 15) aev[nl][ln] = evf[n * EVD + ln] + dv;
        } else {
            catT[ln][nl] = 0.f; catT[64 + ln][nl] = 0.f;
            if (ln < 4)  catT[128 + ln][nl] = 0.f;
            if (ln < 15) aev[nl][ln] = 0.f;
        }
    }
    if (t < FNT) catT[135][t] = 0.0f;
    __syncthreads();
    if (t < FNT * 3) {
        int nl = t / 3, k = t - nl * 3;
        int lo = (k == 0) ? 0 : ((k == 1) ? 3 : 8);
        int hi = (k == 0) ? 3 : ((k == 1) ? 8 : 15);
        float s = 0.f;
        for (int m = lo; m < hi; ++m) { float v = aev[nl][m]; s = fmaf(v, v, s); }
        catT[FD + k][nl] = s;
    }

    const int q = t % 34, g = t / 34;
    const int jb = q * 4, nb = g * 4;
    const bool act = (g < 7);
    float acc[4][4] = {};
    for (int ch = 0; ch < 3; ++ch) {
        __syncthreads();   // prior chunk reads (and, ch=0, evi2 writes) done
        const int rbase = ch * 45;
        for (int idx = t; idx < 45 * 136; idx += 256) {
            int r = idx / 136, j = idx - r * 136;
            wb[idx] = (j < 135) ? Wint[(rbase + r) * 135 + j] : 0.0f;
        }
        __syncthreads();
        if (act) {
            for (int c = 0; c < 45; ++c) {
                const float4 w = *(const float4*)&wb[c * 136 + jb];
                const float4 x = *(const float4*)&catT[rbase + c][nb];
                const float xs[4] = {x.x, x.y, x.z, x.w};
                const float ws[4] = {w.x, w.y, w.z, w.w};
                #pragma unroll
                for (int r = 0; r < 4; ++r)
                    #pragma unroll
                    for (int cc = 0; cc < 4; ++cc)
                        acc[r][cc] = fmaf(ws[cc], xs[r], acc[r][cc]);
            }
        }
    }
    if (act) {
        #pragma unroll
        for (int c = 0; c < 4; ++c) {
            int j = jb + c;
            if (j >= 135) break;
            float bj = bint[j];
            #pragma unroll
            for (int r = 0; r < 4; ++r) {
                int n = n0 + nb + r;
                if (n >= NN) continue;
                float a = acc[r][c] + bj;
                if (j < FD) out[n * FD + j] = catT[j][nb + r] + a;  // att_inv + d_inv2
                else        tacc[nb + r][j - FD] = a;               // b_ev
            }
        }
    }
    __syncthreads();
    for (int idx = t; idx < FNT * EVD; idx += 256) {
        int nl = idx / EVD, m = idx - nl * EVD;
        int n = n0 + nl;
        if (n >= NN) continue;
        int hd = (m < 3) ? 0 : ((m < 8) ? 1 : 2);
        out[NN * FD + n * EVD + m] = aev[nl][m] * (1.0f + tacc[nl][hd]);
    }
}

extern "C" void kernel_launch(void* const* d_in, const int* in_sizes, int n_in,
                              void* d_out, int out_size, void* d_ws, size_t ws_size,
                              hipStream_t stream)
{
    (void)in_sizes; (void)n_in; (void)out_size; (void)ws_size;
    const float* xin  = (const float*)d_in[0];
    const float* evf  = (const float*)d_in[1];
    const float* rbf  = (const float*)d_in[2];
    const int*   snd  = (const int*)d_in[3];
    const int*   rcv  = (const int*)d_in[4];
    const float* sh   = (const float*)d_in[5];
    const float* cut  = (const float*)d_in[6];
    const float* Wint = (const float*)d_in[28];
    const float* bint = (const float*)d_in[29];

    float* ws     = (float*)d_ws;
    float* qinv   = ws;                        // NN*FD = 2,640,000
    float* kinv   = qinv   + NN * FD;
    float* vinv   = kinv   + NN * FD;
    float* qev    = vinv   + NN * FD;
    float* kev    = qev    + NN * FD;
    float* evi    = kev    + NN * FD;          // NE*3
    float* alphaI = evi    + NE * 3;           // NE*4
    float* alphaE = alphaI + NE * 4;           // NE*4
    int*   iwork  = (int*)(alphaE + NE * 4);
    int*   roff   = iwork;                     // NN+1
    int*   cnt_cursor = roff + (NN + 1);       // NN (counts, then cursor)
    int*   eid    = cnt_cursor + NN;           // NE
    // pad int region to 240,004 so weights stay 16B-aligned
    float* wtail  = (float*)(iwork + 240004);

    unsigned short* W2Tfi = (unsigned short*)wtail;        // 27648 bf16
    unsigned short* W2Tfe = W2Tfi + NP * KG;               // 27648
    unsigned short* W1Tfi = W2Tfe + NP * KG;               // 4608
    unsigned short* W1Tfe = W1Tfi + NP * RB;               // 4608
    float* WqP = (float*)(W1Tfe + NP * RB);                // 4752 f32 each
    float* WkP = WqP + 4 * 33 * 36;
    float* WvP = WkP + 4 * 33 * 36;
    // total ws use ~62.8 MB (< 67.1 MB proven available in rounds 2-7)

    // ---- CSR build ----
    hipMemsetAsync(cnt_cursor, 0, (size_t)NN * sizeof(int), stream);
    k_hist<<<(NE + 255) / 256, 256, 0, stream>>>(rcv, cnt_cursor);
    k_scan<<<1, 256, 0, stream>>>(cnt_cursor, roff);
    k_fill<<<(NE + 255) / 256, 256, 0, stream>>>(rcv, cnt_cursor, eid);

    k_prep<<<64, 256, 0, stream>>>(
        (const float*)d_in[7], (const float*)d_in[8], (const float*)d_in[9],
        (const float*)d_in[12], (const float*)d_in[14], (const float*)d_in[18],
        (const float*)d_in[20], (const float*)d_in[22], (const float*)d_in[26],
        W1Tfi, W1Tfe, W2Tfi, W2Tfe, WqP, WkP, WvP);

    k_proj<<<(NN + PNT - 1) / PNT, 256, 0, stream>>>(
        xin, WqP, WkP, WvP,
        (const float*)d_in[10], (const float*)d_in[11],
        qinv, kinv, vinv, qev, kev);
    k_evi<<<(NE + 255) / 256, 256, 0, stream>>>(evf, snd, rcv, evi);

    const int nt = NE / TE;  // 3125, exact
    k_edge<0><<<nt, 256, 0, stream>>>(rbf, evi, snd, rcv, cut,
        W1Tfi, (const float*)d_in[13], W2Tfi, (const float*)d_in[15],
        (const float*)d_in[16], (const float*)d_in[17], (const float*)d_in[19],
        qinv, kinv, alphaI);
    k_edge<1><<<nt, 256, 0, stream>>>(rbf, evi, snd, rcv, cut,
        W1Tfe, (const float*)d_in[21], W2Tfe, (const float*)d_in[23],
        (const float*)d_in[24], (const float*)d_in[25], (const float*)d_in[27],
        qev, kev, alphaE);

    k_final<<<(NN + FNT - 1) / FNT, 256, 0, stream>>>(
        xin, evf, vinv, sh, alphaI, alphaE, roff, eid, snd,
        Wint, bint, (float*)d_out);
}

// Round 10
// 657.772 us; speedup vs baseline: 1.1613x; 1.1613x over previous
//
#include <hip/hip_runtime.h>

// Euclidean transformer layer, MI355X, round 9.
// Receiver-sorted edge processing end-to-end: CSR sort -> sorted per-edge
// streams (evi/cut/snd/rcv) -> k_edge (MFMA filters, q-gathers get L2
// locality, alpha written at sorted pos) -> k_final (streamed meta, x2
// unrolled v-gather, Wint direct from global, high occupancy).

#define NN 20000
#define NE 200000
#define FD 132
#define RB 32
#define EVD 15
#define TE 64      // edges per block (200000 = 3125 * 64, exact)
#define KPAD 200   // HT LDS k-stride in bf16
#define KG 192     // global W2T k-stride
#define NP 144     // padded n (132 -> 9 tiles of 16)
#define PNT 28     // nodes per block in k_proj
#define FNT 28     // nodes per block in k_final

typedef __attribute__((ext_vector_type(8))) short bf16x8;
typedef __attribute__((ext_vector_type(4))) float f32x4;

__device__ __forceinline__ float silu_f(float x) {
    return x / (1.0f + __expf(-x));
}
__device__ __forceinline__ unsigned short f2bf(float x) {
    union { float f; unsigned u; } v; v.f = x;
    unsigned r = v.u + 0x7FFF + ((v.u >> 16) & 1);   // RNE
    return (unsigned short)(r >> 16);
}

// ---------------- prep: weight reshape/convert (idempotent, every call) ------
__global__ __launch_bounds__(256) void k_prep(
    const float* __restrict__ Wq, const float* __restrict__ Wk, const float* __restrict__ Wv,
    const float* __restrict__ fiW1, const float* __restrict__ fiW2, const float* __restrict__ fiWe2,
    const float* __restrict__ feW1, const float* __restrict__ feW2, const float* __restrict__ feWe2,
    unsigned short* __restrict__ W1Tfi, unsigned short* __restrict__ W1Tfe,
    unsigned short* __restrict__ W2Tfi, unsigned short* __restrict__ W2Tfe,
    float* __restrict__ WqP, float* __restrict__ WkP, float* __restrict__ WvP)
{
    const int gid = blockIdx.x * 256 + threadIdx.x;
    const int gs  = gridDim.x * 256;
    for (int idx = gid; idx < NP * RB; idx += gs) {
        int n = idx / RB, k = idx - n * RB;
        W1Tfi[idx] = f2bf((n < FD) ? fiW1[k * FD + n] : 0.0f);
        W1Tfe[idx] = f2bf((n < FD) ? feW1[k * FD + n] : 0.0f);
    }
    for (int idx = gid; idx < NP * KG; idx += gs) {
        int n = idx / KG, k = idx - n * KG;
        float vi = 0.0f, ve = 0.0f;
        if (n < FD) {
            if (k < FD)       { vi = fiW2[k * FD + n];          ve = feW2[k * FD + n]; }
            else if (k < 165) { vi = fiWe2[(k - FD) * FD + n];  ve = feWe2[(k - FD) * FD + n]; }
        }
        W2Tfi[idx] = f2bf(vi);
        W2Tfe[idx] = f2bf(ve);
    }
    for (int idx = gid; idx < 4 * 33 * 36; idx += gs) {
        int H = idx / (33 * 36), rem = idx - H * (33 * 36);
        int i = rem / 36, jp = rem - i * 36;
        float q = 0.f, k = 0.f, v = 0.f;
        if (jp < 33) {
            q = Wq[H * 1089 + i * 33 + jp];
            k = Wk[H * 1089 + i * 33 + jp];
            v = Wv[H * 1089 + i * 33 + jp];
        }
        WqP[idx] = q; WkP[idx] = k; WvP[idx] = v;
    }
}

// ---------------- CSR build: counting sort by receiver -----------------------
__global__ __launch_bounds__(256) void k_hist(const int* __restrict__ rcv,
                                              int* __restrict__ cnt)
{
    int e = blockIdx.x * 256 + threadIdx.x;
    if (e < NE) atomicAdd(&cnt[rcv[e]], 1);
}

__global__ __launch_bounds__(1024) void k_scan(int* __restrict__ cnt_cursor,
                                               int* __restrict__ roff)
{
    __shared__ int sums[1024];
    const int t = threadIdx.x;
    const int base = t * 20;
    int loc[20];
    int s = 0;
    #pragma unroll
    for (int i = 0; i < 20; ++i) {
        int idx = base + i;
        int v = (idx < NN) ? cnt_cursor[idx] : 0;
        loc[i] = s; s += v;
    }
    sums[t] = s;
    __syncthreads();
    for (int off = 1; off < 1024; off <<= 1) {
        int v2 = (t >= off) ? sums[t - off] : 0;
        __syncthreads();
        sums[t] += v2;
        __syncthreads();
    }
    int ex = (t > 0) ? sums[t - 1] : 0;
    #pragma unroll
    for (int i = 0; i < 20; ++i) {
        int idx = base + i;
        if (idx < NN) { roff[idx] = ex + loc[i]; cnt_cursor[idx] = ex + loc[i]; }
    }
    if (t == 1023) roff[NN] = sums[1023];
}

__global__ __launch_bounds__(256) void k_fill(const int* __restrict__ rcv,
                                              int* __restrict__ cursor,
                                              int* __restrict__ eid)
{
    int e = blockIdx.x * 256 + threadIdx.x;
    if (e < NE) {
        int p = atomicAdd(&cursor[rcv[e]], 1);
        eid[p] = e;
    }
}

// ---------------- sorted per-edge streams + SO(3) invariants -----------------
__global__ __launch_bounds__(256) void k_eprep(
    const float* __restrict__ ev, const int* __restrict__ snd,
    const int* __restrict__ rcv, const float* __restrict__ cut,
    const int* __restrict__ eid,
    float* __restrict__ evi_s, float* __restrict__ cut_s,
    int* __restrict__ ss, int* __restrict__ rs)
{
    int p = blockIdx.x * 256 + threadIdx.x;
    if (p >= NE) return;
    int e = eid[p];
    int s = snd[e], r = rcv[e];
    ss[p] = s; rs[p] = r; cut_s[p] = cut[e];
    const float* ps = &ev[s * EVD];
    const float* pr = &ev[r * EVD];
    float s0 = 0.f, s1 = 0.f, s2 = 0.f;
    #pragma unroll
    for (int m = 0; m < 3; ++m)  { float d = ps[m] - pr[m]; s0 = fmaf(d, d, s0); }
    #pragma unroll
    for (int m = 3; m < 8; ++m)  { float d = ps[m] - pr[m]; s1 = fmaf(d, d, s1); }
    #pragma unroll
    for (int m = 8; m < 15; ++m) { float d = ps[m] - pr[m]; s2 = fmaf(d, d, s2); }
    evi_s[p * 3 + 0] = s0; evi_s[p * 3 + 1] = s1; evi_s[p * 3 + 2] = s2;
}

// ---------------- node projections: LDS weights + 4x4 register tile ----------
__device__ __forceinline__ void proj_inv_pass(
    const float* __restrict__ wb, const float (*__restrict__ xT)[PNT],
    float* __restrict__ outp, int t, int n0)
{
    const int q = t % 36, g = t / 36;
    if (g >= 7) return;
    const int H = q / 9, jb = (q - H * 9) * 4, nb = g * 4;
    const int fb = H * 33;
    float acc[4][4] = {};
    for (int i = 0; i < 33; ++i) {
        const float4 w = *(const float4*)&wb[(fb + i) * 36 + jb];
        const float4 x = *(const float4*)&xT[fb + i][nb];
        const float xs[4] = {x.x, x.y, x.z, x.w};
        const float ws[4] = {w.x, w.y, w.z, w.w};
        #pragma unroll
        for (int r = 0; r < 4; ++r)
            #pragma unroll
            for (int c = 0; c < 4; ++c)
                acc[r][c] = fmaf(ws[c], xs[r], acc[r][c]);
    }
    #pragma unroll
    for (int c = 0; c < 4; ++c) {
        int jj = jb + c;
        if (jj >= 33) break;
        int j = H * 33 + jj;
        #pragma unroll
        for (int r = 0; r < 4; ++r) {
            int n = n0 + nb + r;
            if (n < NN) outp[n * FD + j] = acc[r][c];
        }
    }
}

__device__ __forceinline__ void proj_ev_pass(
    const float* __restrict__ wb, const float (*__restrict__ xT)[PNT],
    float* __restrict__ outp, int t, int n0)
{
    const int q = t % 33, g = t / 33;
    if (g >= 7) return;
    const int H = q / 11, jb = (q - H * 11) * 4, nb = g * 4;
    const int fb = H * 44;
    float acc[4][4] = {};
    for (int i = 0; i < 44; ++i) {
        const float4 w = *(const float4*)&wb[(fb + i) * 44 + jb];
        const float4 x = *(const float4*)&xT[fb + i][nb];
        const float xs[4] = {x.x, x.y, x.z, x.w};
        const float ws[4] = {w.x, w.y, w.z, w.w};
        #pragma unroll
        for (int r = 0; r < 4; ++r)
            #pragma unroll
            for (int c = 0; c < 4; ++c)
                acc[r][c] = fmaf(ws[c], xs[r], acc[r][c]);
    }
    #pragma unroll
    for (int c = 0; c < 4; ++c) {
        int j = fb + jb + c;
        #pragma unroll
        for (int r = 0; r < 4; ++r) {
            int n = n0 + nb + r;
            if (n < NN) outp[n * FD + j] = acc[r][c];
        }
    }
}

__global__ __launch_bounds__(256) void k_proj(
    const float* __restrict__ xin,
    const float* __restrict__ WqP, const float* __restrict__ WkP, const float* __restrict__ WvP,
    const float* __restrict__ Wqe, const float* __restrict__ Wke,
    float* __restrict__ qinv, float* __restrict__ kinv, float* __restrict__ vinv,
    float* __restrict__ qev, float* __restrict__ kev)
{
    __shared__ __align__(16) float xT[FD][PNT];
    __shared__ __align__(16) float wb[5808];
    const int t = threadIdx.x;
    const int n0 = blockIdx.x * PNT;

    for (int idx = t; idx < PNT * FD; idx += 256) {
        int nl = idx / FD, j = idx - nl * FD;
        int n = n0 + nl;
        xT[j][nl] = (n < NN) ? xin[n * FD + j] : 0.0f;
    }
    for (int idx = t; idx < 4752; idx += 256) wb[idx] = WqP[idx];
    __syncthreads();
    proj_inv_pass(wb, xT, qinv, t, n0);
    __syncthreads();
    for (int idx = t; idx < 4752; idx += 256) wb[idx] = WkP[idx];
    __syncthreads();
    proj_inv_pass(wb, xT, kinv, t, n0);
    __syncthreads();
    for (int idx = t; idx < 4752; idx += 256) wb[idx] = WvP[idx];
    __syncthreads();
    proj_inv_pass(wb, xT, vinv, t, n0);
    __syncthreads();
    for (int idx = t; idx < 5808; idx += 256) wb[idx] = Wqe[idx];
    __syncthreads();
    proj_ev_pass(wb, xT, qev, t, n0);
    __syncthreads();
    for (int idx = t; idx < 5808; idx += 256) wb[idx] = Wke[idx];
    __syncthreads();
    proj_ev_pass(wb, xT, kev, t, n0);
}

// ---------------- fused edge kernel (sorted order): MFMA filter + alpha ------
// PATH 0: inv (4 heads x 33), PATH 1: ev (3 heads x 44).
template<int PATH>
__global__ __launch_bounds__(256, 4) void k_edge(
    const float* __restrict__ rbf, const float* __restrict__ evi_s,
    const int* __restrict__ eid, const int* __restrict__ ss,
    const int* __restrict__ rs, const float* __restrict__ cut_s,
    const unsigned short* __restrict__ W1T,  // [144][32] bf16
    const float* __restrict__ b1,
    const unsigned short* __restrict__ W2T,  // [144][192] bf16
    const float* __restrict__ b2,
    const float* __restrict__ We1, const float* __restrict__ be1,
    const float* __restrict__ be2,
    const float* __restrict__ qt, const float* __restrict__ kt,
    float* __restrict__ aout)
{
    constexpr int   DH = (PATH == 0) ? 33 : 44;
    constexpr float SC = (PATH == 0) ? 0.17407765595569785f : 0.15075567228888181f;

    // lds_buf: HT [64][200] bf16 (25.6KB) then aliased FW [64][132] f32 (33.8KB)
    __shared__ __align__(16) char lds_buf[TE * FD * 4];
    __shared__ float evl[TE * 3];
    __shared__ int   sl[TE];
    __shared__ int   rl[TE];
    __shared__ float cl[TE];

    typedef unsigned short (*HTp)[KPAD];
    HTp HT    = (HTp)lds_buf;
    float* FW = (float*)lds_buf;

    const int t    = threadIdx.x;
    const int wv   = t >> 6;
    const int ln   = t & 63;
    const int lrow = ln & 15;
    const int kseg = ln >> 4;
    const int p0   = blockIdx.x * TE;

    // A-frag: rbf row gathered via eid (sorted order)
    const int  prow = p0 + 16 * wv + lrow;
    const int  eorg = eid[prow];
    const float4 ra = *(const float4*)&rbf[(size_t)eorg * RB + kseg * 8];
    const float4 rb = *(const float4*)&rbf[(size_t)eorg * RB + kseg * 8 + 4];

    if (t < TE) {
        sl[t] = ss[p0 + t];
        rl[t] = rs[p0 + t];
        cl[t] = cut_s[p0 + t];
    }
    for (int idx = t; idx < TE * 3; idx += 256) evl[idx] = evi_s[p0 * 3 + idx];
    __syncthreads();

    // ---- H-GEMM: h = silu(rbf @ W1 + b1) ----
    {
        bf16x8 afrag;
        afrag[0] = (short)f2bf(ra.x); afrag[1] = (short)f2bf(ra.y);
        afrag[2] = (short)f2bf(ra.z); afrag[3] = (short)f2bf(ra.w);
        afrag[4] = (short)f2bf(rb.x); afrag[5] = (short)f2bf(rb.y);
        afrag[6] = (short)f2bf(rb.z); afrag[7] = (short)f2bf(rb.w);
        #pragma unroll
        for (int nt = 0; nt < 9; ++nt) {
            const int ncol = nt * 16 + lrow;
            bf16x8 bfrag = *(const bf16x8*)&W1T[ncol * RB + kseg * 8];
            f32x4 acc = {0.f, 0.f, 0.f, 0.f};
            acc = __builtin_amdgcn_mfma_f32_16x16x32_bf16(afrag, bfrag, acc, 0, 0, 0);
            if (ncol < FD) {
                const float bias = b1[ncol];
                #pragma unroll
                for (int r = 0; r < 4; ++r)
                    HT[16 * wv + kseg * 4 + r][ncol] = f2bf(silu_f(acc[r] + bias));
            }
        }
    }
    // g rows 132..164: silu(evi @ We1 + be1)
    for (int idx = t; idx < TE * 33; idx += 256) {
        int e = idx / 33, ii = idx - e * 33;
        float a = be1[ii];
        a = fmaf(evl[e * 3 + 0], We1[ii], a);
        a = fmaf(evl[e * 3 + 1], We1[33 + ii], a);
        a = fmaf(evl[e * 3 + 2], We1[66 + ii], a);
        HT[e][FD + ii] = f2bf(silu_f(a));
    }
    // zero-pad k 165..199
    for (int idx = t; idx < TE * (KPAD - 165); idx += 256) {
        int e = idx / (KPAD - 165), kk = idx - e * (KPAD - 165);
        HT[e][165 + kk] = 0;
    }
    __syncthreads();

    // ---- main GEMM: fw[64][132] = Hext[64][165] @ Wcat[165][132] ----
    f32x4 acc[9];
    #pragma unroll
    for (int nt = 0; nt < 9; ++nt) acc[nt] = (f32x4){0.f, 0.f, 0.f, 0.f};
    {
        const unsigned short* hrow = &HT[16 * wv + lrow][0];
        #pragma unroll
        for (int kt = 0; kt < 6; ++kt) {
            bf16x8 afrag = *(const bf16x8*)&hrow[kt * 32 + kseg * 8];
            #pragma unroll
            for (int nt = 0; nt < 9; ++nt) {
                bf16x8 bfrag = *(const bf16x8*)&W2T[(nt * 16 + lrow) * KG + kt * 32 + kseg * 8];
                acc[nt] = __builtin_amdgcn_mfma_f32_16x16x32_bf16(afrag, bfrag, acc[nt], 0, 0, 0);
            }
        }
    }
    __syncthreads();   // HT dead; safe to overwrite as FW

    #pragma unroll
    for (int nt = 0; nt < 9; ++nt) {
        const int ncol = nt * 16 + lrow;
        if (ncol < FD) {
            const float bias = b2[ncol] + be2[ncol];
            #pragma unroll
            for (int r = 0; r < 4; ++r)
                FW[(16 * wv + kseg * 4 + r) * FD + ncol] = acc[nt][r] + bias;
        }
    }
    __syncthreads();

    // ---- fused qk*fw head-sums -> alpha at sorted position ----
    // thread t: edge eq = t>>2, j-chunk jb = (t&3)*33 .. +32
    {
        const int eq = t >> 2;
        const int m  = t & 3;
        const int jb = m * 33;
        const float* qp = qt + (size_t)rl[eq] * FD + jb;
        const float* kp = kt + (size_t)sl[eq] * FD + jb;
        const float* fp = &FW[eq * FD + jb];
        // split point within chunk for upper head (PATH1); PATH0: all lower
        const int hlo   = jb / DH;
        const int split = (PATH == 0) ? 33 : (DH * (hlo + 1) - jb);
        float pa = 0.f, pb = 0.f;
        #pragma unroll
        for (int jj = 0; jj < 33; ++jj) {
            float f = fp[jj] * qp[jj] * kp[jj];
            if (jj < split) pa += f; else pb += f;
        }
        float nxt = __shfl_down(pa, 1);
        if (PATH == 0) {
            aout[(size_t)(p0 + eq) * 4 + m] = pa * cl[eq] * SC;
        } else {
            if (m < 3) {
                float a = ((m == 0) ? pa : pb) + nxt;
                aout[(size_t)(p0 + eq) * 4 + m] = a * cl[eq] * SC;
            }
        }
    }
}

// ---------------- final node update: streamed CSR gather + Wint GEMM ---------
__global__ __launch_bounds__(256) void k_final(
    const float* __restrict__ xin, const float* __restrict__ evf,
    const float* __restrict__ vt, const float* __restrict__ sh,
    const float* __restrict__ alphaI, const float* __restrict__ alphaE,
    const int* __restrict__ roff, const int* __restrict__ eid,
    const int* __restrict__ ss,
    const float* __restrict__ Wint, const float* __restrict__ bint,
    float* __restrict__ out)
{
    __shared__ __align__(16) float catT[136][FNT];  // 15.2 KB
    __shared__ float aev[FNT][16];
    __shared__ float tacc[FNT][4];
    const int t = threadIdx.x;
    const int n0 = blockIdx.x * FNT;
    const int wv = t >> 6, ln = t & 63;

    // ---- aggregation: one wave per node; meta streamed (sorted), x2 unroll --
    const int h0 = ln / 33;
    const int h1 = (64 + ln) / 33;
    const int hm = (ln < 3) ? 0 : ((ln < 8) ? 1 : 2);
    for (int nl = wv; nl < FNT; nl += 4) {
        const int n = n0 + nl;
        float a0 = 0.f, a1 = 0.f, a2 = 0.f, dv = 0.f;
        if (n < NN) {
            const int pend = roff[n + 1];
            int p = roff[n];
            for (; p + 2 <= pend; p += 2) {
                const int sA = ss[p], sB = ss[p + 1];
                const int eA = eid[p], eB = eid[p + 1];
                const float* vA = vt + (size_t)sA * FD;
                const float* vB = vt + (size_t)sB * FD;
                const float aA0 = alphaI[(size_t)p * 4 + h0];
                const float aB0 = alphaI[(size_t)(p + 1) * 4 + h0];
                const float aA1 = alphaI[(size_t)p * 4 + h1];
                const float aB1 = alphaI[(size_t)(p + 1) * 4 + h1];
                a0 = fmaf(aA0, vA[ln], a0);      a0 = fmaf(aB0, vB[ln], a0);
                a1 = fmaf(aA1, vA[64 + ln], a1); a1 = fmaf(aB1, vB[64 + ln], a1);
                if (ln < 4) {
                    a2 = fmaf(alphaI[(size_t)p * 4 + 3], vA[128 + ln], a2);
                    a2 = fmaf(alphaI[(size_t)(p + 1) * 4 + 3], vB[128 + ln], a2);
                }
                if (ln < 15) {
                    dv = fmaf(alphaE[(size_t)p * 4 + hm], sh[(size_t)eA * EVD + ln], dv);
                    dv = fmaf(alphaE[(size_t)(p + 1) * 4 + hm], sh[(size_t)eB * EVD + ln], dv);
                }
            }
            for (; p < pend; ++p) {
                const int sA = ss[p];
                const int eA = eid[p];
                const float* vA = vt + (size_t)sA * FD;
                a0 = fmaf(alphaI[(size_t)p * 4 + h0], vA[ln], a0);
                a1 = fmaf(alphaI[(size_t)p * 4 + h1], vA[64 + ln], a1);
                if (ln < 4)  a2 = fmaf(alphaI[(size_t)p * 4 + 3], vA[128 + ln], a2);
                if (ln < 15) dv = fmaf(alphaE[(size_t)p * 4 + hm], sh[(size_t)eA * EVD + ln], dv);
            }
            catT[ln][nl]      = xin[n * FD + ln]      + a0;
            catT[64 + ln][nl] = xin[n * FD + 64 + ln] + a1;
            if (ln < 4)  catT[128 + ln][nl] = xin[n * FD + 128 + ln] + a2;
            if (ln < 15) aev[nl][ln] = evf[n * EVD + ln] + dv;
        } else {
            catT[ln][nl] = 0.f; catT[64 + ln][nl] = 0.f;
            if (ln < 4)  catT[128 + ln][nl] = 0.f;
            if (ln < 15) aev[nl][ln] = 0.f;
        }
    }
    if (t < FNT) catT[135][t] = 0.0f;
    __syncthreads();
    if (t < FNT * 3) {
        int nl = t / 3, k = t - nl * 3;
        int lo = (k == 0) ? 0 : ((k == 1) ? 3 : 8);
        int hi = (k == 0) ? 3 : ((k == 1) ? 8 : 15);
        float s = 0.f;
        for (int m = lo; m < hi; ++m) { float v = aev[nl][m]; s = fmaf(v, v, s); }
        catT[FD + k][nl] = s;
    }
    __syncthreads();

    // ---- Wint GEMM: direct global W reads, 4x4 register tile ----
    const int q = t % 34, g = t / 34;
    const int jb = q * 4, nb = g * 4;
    const bool act = (g < 7);
    float acc[4][4] = {};
    if (act) {
        #pragma unroll 5
        for (int c = 0; c < 135; ++c) {
            const float* wr = Wint + c * 135 + jb;
            const float w0 = wr[0];
            const float w1 = wr[1];
            const float w2 = wr[2];
            const float w3 = (jb + 3 < 135) ? wr[3] : 0.f;
            const float4 x = *(const float4*)&catT[c][nb];
            const float xs[4] = {x.x, x.y, x.z, x.w};
            #pragma unroll
            for (int r = 0; r < 4; ++r) {
                acc[r][0] = fmaf(w0, xs[r], acc[r][0]);
                acc[r][1] = fmaf(w1, xs[r], acc[r][1]);
                acc[r][2] = fmaf(w2, xs[r], acc[r][2]);
                acc[r][3] = fmaf(w3, xs[r], acc[r][3]);
            }
        }
        #pragma unroll
        for (int c = 0; c < 4; ++c) {
            int j = jb + c;
            if (j >= 135) break;
            float bj = bint[j];
            #pragma unroll
            for (int r = 0; r < 4; ++r) {
                int n = n0 + nb + r;
                if (n >= NN) continue;
                float a = acc[r][c] + bj;
                if (j < FD) out[n * FD + j] = catT[j][nb + r] + a;  // att_inv + d_inv2
                else        tacc[nb + r][j - FD] = a;               // b_ev
            }
        }
    }
    __syncthreads();
    for (int idx = t; idx < FNT * EVD; idx += 256) {
        int nl = idx / EVD, m = idx - nl * EVD;
        int n = n0 + nl;
        if (n >= NN) continue;
        int hd = (m < 3) ? 0 : ((m < 8) ? 1 : 2);
        out[NN * FD + n * EVD + m] = aev[nl][m] * (1.0f + tacc[nl][hd]);
    }
}

extern "C" void kernel_launch(void* const* d_in, const int* in_sizes, int n_in,
                              void* d_out, int out_size, void* d_ws, size_t ws_size,
                              hipStream_t stream)
{
    (void)in_sizes; (void)n_in; (void)out_size; (void)ws_size;
    const float* xin  = (const float*)d_in[0];
    const float* evf  = (const float*)d_in[1];
    const float* rbf  = (const float*)d_in[2];
    const int*   snd  = (const int*)d_in[3];
    const int*   rcv  = (const int*)d_in[4];
    const float* sh   = (const float*)d_in[5];
    const float* cut  = (const float*)d_in[6];
    const float* Wint = (const float*)d_in[28];
    const float* bint = (const float*)d_in[29];

    float* ws     = (float*)d_ws;
    float* qinv   = ws;                        // NN*FD
    float* kinv   = qinv   + NN * FD;
    float* vinv   = kinv   + NN * FD;
    float* qev    = vinv   + NN * FD;
    float* kev    = qev    + NN * FD;
    float* alphaI = kev    + NN * FD;          // NE*4
    float* alphaE = alphaI + NE * 4;           // NE*4
    float* evi_s  = alphaE + NE * 4;           // NE*3
    float* cut_s  = evi_s  + NE * 3;           // NE
    int*   iwork  = (int*)(cut_s + NE);
    int*   roff   = iwork;                     // NN+1
    int*   cnt_cursor = roff + (NN + 1);       // NN
    int*   eid    = cnt_cursor + NN;           // NE
    int*   ss     = eid + NE;                  // NE
    int*   rs     = ss + NE;                   // NE
    float* wtail  = (float*)(iwork + 640004);  // pad: 16B alignment

    unsigned short* W2Tfi = (unsigned short*)wtail;        // 27648 bf16
    unsigned short* W2Tfe = W2Tfi + NP * KG;               // 27648
    unsigned short* W1Tfi = W2Tfe + NP * KG;               // 4608
    unsigned short* W1Tfe = W1Tfi + NP * RB;               // 4608
    float* WqP = (float*)(W1Tfe + NP * RB);                // 4752 f32 each
    float* WkP = WqP + 4 * 33 * 36;
    float* WvP = WkP + 4 * 33 * 36;
    // total ws ~65.2 MB (< 67.1 MB proven available)

    // ---- CSR build + sorted streams ----
    hipMemsetAsync(cnt_cursor, 0, (size_t)NN * sizeof(int), stream);
    k_hist<<<(NE + 255) / 256, 256, 0, stream>>>(rcv, cnt_cursor);
    k_scan<<<1, 1024, 0, stream>>>(cnt_cursor, roff);
    k_fill<<<(NE + 255) / 256, 256, 0, stream>>>(rcv, cnt_cursor, eid);
    k_eprep<<<(NE + 255) / 256, 256, 0, stream>>>(evf, snd, rcv, cut, eid,
                                                  evi_s, cut_s, ss, rs);

    k_prep<<<64, 256, 0, stream>>>(
        (const float*)d_in[7], (const float*)d_in[8], (const float*)d_in[9],
        (const float*)d_in[12], (const float*)d_in[14], (const float*)d_in[18],
        (const float*)d_in[20], (const float*)d_in[22], (const float*)d_in[26],
        W1Tfi, W1Tfe, W2Tfi, W2Tfe, WqP, WkP, WvP);

    k_proj<<<(NN + PNT - 1) / PNT, 256, 0, stream>>>(
        xin, WqP, WkP, WvP,
        (const float*)d_in[10], (const float*)d_in[11],
        qinv, kinv, vinv, qev, kev);

    const int nt = NE / TE;  // 3125, exact
    k_edge<0><<<nt, 256, 0, stream>>>(rbf, evi_s, eid, ss, rs, cut_s,
        W1Tfi, (const float*)d_in[13], W2Tfi, (const float*)d_in[15],
        (const float*)d_in[16], (const float*)d_in[17], (const float*)d_in[19],
        qinv, kinv, alphaI);
    k_edge<1><<<nt, 256, 0, stream>>>(rbf, evi_s, eid, ss, rs, cut_s,
        W1Tfe, (const float*)d_in[21], W2Tfe, (const float*)d_in[23],
        (const float*)d_in[24], (const float*)d_in[25], (const float*)d_in[27],
        qev, kev, alphaE);

    k_final<<<(NN + FNT - 1) / FNT, 256, 0, stream>>>(
        xin, evf, vinv, sh, alphaI, alphaE, roff, eid, ss,
        Wint, bint, (float*)d_out);
}

// Round 11
// 646.070 us; speedup vs baseline: 1.1824x; 1.0181x over previous
//
#include <hip/hip_runtime.h>

// Euclidean transformer layer, MI355X, round 11.
// k_edge2: BOTH filter paths fused in one kernel, wave-private 16-edge tiles
// (1 wave/block, barriers are free, ~16 independent blocks/CU for latency
// hiding; round-10 counters showed k_edge latency-bound: VALU 19%, MFMA 3.5%,
// HBM 6%, occ 40%). rbf + meta staged once for both paths.

#define NN 20000
#define NE 200000
#define FD 132
#define RB 32
#define EVD 15
#define WE 16      // edges per wave-block (200000 = 12500 * 16, exact)
#define KPAD 200   // HT LDS k-stride in bf16
#define KG 192     // global W2T k-stride
#define NP 144     // padded n (132 -> 9 tiles of 16)
#define PNT 28     // nodes per block in k_proj
#define FNT 28     // nodes per block in k_final

typedef __attribute__((ext_vector_type(8))) short bf16x8;
typedef __attribute__((ext_vector_type(4))) float f32x4;

__device__ __forceinline__ float silu_f(float x) {
    return x / (1.0f + __expf(-x));
}
__device__ __forceinline__ unsigned short f2bf(float x) {
    union { float f; unsigned u; } v; v.f = x;
    unsigned r = v.u + 0x7FFF + ((v.u >> 16) & 1);   // RNE
    return (unsigned short)(r >> 16);
}

// ---------------- prep: weight reshape/convert (idempotent, every call) ------
__global__ __launch_bounds__(256) void k_prep(
    const float* __restrict__ Wq, const float* __restrict__ Wk, const float* __restrict__ Wv,
    const float* __restrict__ fiW1, const float* __restrict__ fiW2, const float* __restrict__ fiWe2,
    const float* __restrict__ feW1, const float* __restrict__ feW2, const float* __restrict__ feWe2,
    unsigned short* __restrict__ W1Tfi, unsigned short* __restrict__ W1Tfe,
    unsigned short* __restrict__ W2Tfi, unsigned short* __restrict__ W2Tfe,
    float* __restrict__ WqP, float* __restrict__ WkP, float* __restrict__ WvP)
{
    const int gid = blockIdx.x * 256 + threadIdx.x;
    const int gs  = gridDim.x * 256;
    for (int idx = gid; idx < NP * RB; idx += gs) {
        int n = idx / RB, k = idx - n * RB;
        W1Tfi[idx] = f2bf((n < FD) ? fiW1[k * FD + n] : 0.0f);
        W1Tfe[idx] = f2bf((n < FD) ? feW1[k * FD + n] : 0.0f);
    }
    for (int idx = gid; idx < NP * KG; idx += gs) {
        int n = idx / KG, k = idx - n * KG;
        float vi = 0.0f, ve = 0.0f;
        if (n < FD) {
            if (k < FD)       { vi = fiW2[k * FD + n];          ve = feW2[k * FD + n]; }
            else if (k < 165) { vi = fiWe2[(k - FD) * FD + n];  ve = feWe2[(k - FD) * FD + n]; }
        }
        W2Tfi[idx] = f2bf(vi);
        W2Tfe[idx] = f2bf(ve);
    }
    for (int idx = gid; idx < 4 * 33 * 36; idx += gs) {
        int H = idx / (33 * 36), rem = idx - H * (33 * 36);
        int i = rem / 36, jp = rem - i * 36;
        float q = 0.f, k = 0.f, v = 0.f;
        if (jp < 33) {
            q = Wq[H * 1089 + i * 33 + jp];
            k = Wk[H * 1089 + i * 33 + jp];
            v = Wv[H * 1089 + i * 33 + jp];
        }
        WqP[idx] = q; WkP[idx] = k; WvP[idx] = v;
    }
}

// ---------------- CSR build: counting sort by receiver -----------------------
__global__ __launch_bounds__(256) void k_hist(const int* __restrict__ rcv,
                                              int* __restrict__ cnt)
{
    int e = blockIdx.x * 256 + threadIdx.x;
    if (e < NE) atomicAdd(&cnt[rcv[e]], 1);
}

__global__ __launch_bounds__(1024) void k_scan(int* __restrict__ cnt_cursor,
                                               int* __restrict__ roff)
{
    __shared__ int sums[1024];
    const int t = threadIdx.x;
    const int base = t * 20;
    int loc[20];
    int s = 0;
    #pragma unroll
    for (int i = 0; i < 20; ++i) {
        int idx = base + i;
        int v = (idx < NN) ? cnt_cursor[idx] : 0;
        loc[i] = s; s += v;
    }
    sums[t] = s;
    __syncthreads();
    for (int off = 1; off < 1024; off <<= 1) {
        int v2 = (t >= off) ? sums[t - off] : 0;
        __syncthreads();
        sums[t] += v2;
        __syncthreads();
    }
    int ex = (t > 0) ? sums[t - 1] : 0;
    #pragma unroll
    for (int i = 0; i < 20; ++i) {
        int idx = base + i;
        if (idx < NN) { roff[idx] = ex + loc[i]; cnt_cursor[idx] = ex + loc[i]; }
    }
    if (t == 1023) roff[NN] = sums[1023];
}

__global__ __launch_bounds__(256) void k_fill(const int* __restrict__ rcv,
                                              int* __restrict__ cursor,
                                              int* __restrict__ eid)
{
    int e = blockIdx.x * 256 + threadIdx.x;
    if (e < NE) {
        int p = atomicAdd(&cursor[rcv[e]], 1);
        eid[p] = e;
    }
}

// ---------------- sorted per-edge streams + SO(3) invariants -----------------
__global__ __launch_bounds__(256) void k_eprep(
    const float* __restrict__ ev, const int* __restrict__ snd,
    const int* __restrict__ rcv, const float* __restrict__ cut,
    const int* __restrict__ eid,
    float* __restrict__ evi_s, float* __restrict__ cut_s,
    int* __restrict__ ss, int* __restrict__ rs)
{
    int p = blockIdx.x * 256 + threadIdx.x;
    if (p >= NE) return;
    int e = eid[p];
    int s = snd[e], r = rcv[e];
    ss[p] = s; rs[p] = r; cut_s[p] = cut[e];
    const float* ps = &ev[s * EVD];
    const float* pr = &ev[r * EVD];
    float s0 = 0.f, s1 = 0.f, s2 = 0.f;
    #pragma unroll
    for (int m = 0; m < 3; ++m)  { float d = ps[m] - pr[m]; s0 = fmaf(d, d, s0); }
    #pragma unroll
    for (int m = 3; m < 8; ++m)  { float d = ps[m] - pr[m]; s1 = fmaf(d, d, s1); }
    #pragma unroll
    for (int m = 8; m < 15; ++m) { float d = ps[m] - pr[m]; s2 = fmaf(d, d, s2); }
    evi_s[p * 3 + 0] = s0; evi_s[p * 3 + 1] = s1; evi_s[p * 3 + 2] = s2;
}

// ---------------- node projections: LDS weights + 4x4 register tile ----------
__device__ __forceinline__ void proj_inv_pass(
    const float* __restrict__ wb, const float (*__restrict__ xT)[PNT],
    float* __restrict__ outp, int t, int n0)
{
    const int q = t % 36, g = t / 36;
    if (g >= 7) return;
    const int H = q / 9, jb = (q - H * 9) * 4, nb = g * 4;
    const int fb = H * 33;
    float acc[4][4] = {};
    for (int i = 0; i < 33; ++i) {
        const float4 w = *(const float4*)&wb[(fb + i) * 36 + jb];
        const float4 x = *(const float4*)&xT[fb + i][nb];
        const float xs[4] = {x.x, x.y, x.z, x.w};
        const float ws[4] = {w.x, w.y, w.z, w.w};
        #pragma unroll
        for (int r = 0; r < 4; ++r)
            #pragma unroll
            for (int c = 0; c < 4; ++c)
                acc[r][c] = fmaf(ws[c], xs[r], acc[r][c]);
    }
    #pragma unroll
    for (int c = 0; c < 4; ++c) {
        int jj = jb + c;
        if (jj >= 33) break;
        int j = H * 33 + jj;
        #pragma unroll
        for (int r = 0; r < 4; ++r) {
            int n = n0 + nb + r;
            if (n < NN) outp[n * FD + j] = acc[r][c];
        }
    }
}

__device__ __forceinline__ void proj_ev_pass(
    const float* __restrict__ wb, const float (*__restrict__ xT)[PNT],
    float* __restrict__ outp, int t, int n0)
{
    const int q = t % 33, g = t / 33;
    if (g >= 7) return;
    const int H = q / 11, jb = (q - H * 11) * 4, nb = g * 4;
    const int fb = H * 44;
    float acc[4][4] = {};
    for (int i = 0; i < 44; ++i) {
        const float4 w = *(const float4*)&wb[(fb + i) * 44 + jb];
        const float4 x = *(const float4*)&xT[fb + i][nb];
        const float xs[4] = {x.x, x.y, x.z, x.w};
        const float ws[4] = {w.x, w.y, w.z, w.w};
        #pragma unroll
        for (int r = 0; r < 4; ++r)
            #pragma unroll
            for (int c = 0; c < 4; ++c)
                acc[r][c] = fmaf(ws[c], xs[r], acc[r][c]);
    }
    #pragma unroll
    for (int c = 0; c < 4; ++c) {
        int j = fb + jb + c;
        #pragma unroll
        for (int r = 0; r < 4; ++r) {
            int n = n0 + nb + r;
            if (n < NN) outp[n * FD + j] = acc[r][c];
        }
    }
}

__global__ __launch_bounds__(256) void k_proj(
    const float* __restrict__ xin,
    const float* __restrict__ WqP, const float* __restrict__ WkP, const float* __restrict__ WvP,
    const float* __restrict__ Wqe, const float* __restrict__ Wke,
    float* __restrict__ qinv, float* __restrict__ kinv, float* __restrict__ vinv,
    float* __restrict__ qev, float* __restrict__ kev)
{
    __shared__ __align__(16) float xT[FD][PNT];
    __shared__ __align__(16) float wb[5808];
    const int t = threadIdx.x;
    const int n0 = blockIdx.x * PNT;

    for (int idx = t; idx < PNT * FD; idx += 256) {
        int nl = idx / FD, j = idx - nl * FD;
        int n = n0 + nl;
        xT[j][nl] = (n < NN) ? xin[n * FD + j] : 0.0f;
    }
    for (int idx = t; idx < 4752; idx += 256) wb[idx] = WqP[idx];
    __syncthreads();
    proj_inv_pass(wb, xT, qinv, t, n0);
    __syncthreads();
    for (int idx = t; idx < 4752; idx += 256) wb[idx] = WkP[idx];
    __syncthreads();
    proj_inv_pass(wb, xT, kinv, t, n0);
    __syncthreads();
    for (int idx = t; idx < 4752; idx += 256) wb[idx] = WvP[idx];
    __syncthreads();
    proj_inv_pass(wb, xT, vinv, t, n0);
    __syncthreads();
    for (int idx = t; idx < 5808; idx += 256) wb[idx] = Wqe[idx];
    __syncthreads();
    proj_ev_pass(wb, xT, qev, t, n0);
    __syncthreads();
    for (int idx = t; idx < 5808; idx += 256) wb[idx] = Wke[idx];
    __syncthreads();
    proj_ev_pass(wb, xT, kev, t, n0);
}

// ---------------- one filter path for a 16-edge wave tile --------------------
// PATH 0: inv (4 heads x 33), PATH 1: ev (3 heads x 44).
template<int PATH>
__device__ __forceinline__ void edge_path(
    bf16x8 afrag,
    unsigned short (*__restrict__ HT)[KPAD], float* __restrict__ FW,
    const float* __restrict__ evl, const int* __restrict__ sl,
    const int* __restrict__ rl, const float* __restrict__ cl,
    const unsigned short* __restrict__ W1T, const float* __restrict__ b1,
    const unsigned short* __restrict__ W2T, const float* __restrict__ b2,
    const float* __restrict__ We1, const float* __restrict__ be1,
    const float* __restrict__ be2,
    const float* __restrict__ qt, const float* __restrict__ kt,
    float* __restrict__ aout,
    int ln, int lrow, int kseg, int p0)
{
    constexpr int   DH = (PATH == 0) ? 33 : 44;
    constexpr float SC = (PATH == 0) ? 0.17407765595569785f : 0.15075567228888181f;

    // ---- H-GEMM: h = silu(rbf @ W1 + b1); D rows = edges (kseg*4+r) ----
    #pragma unroll
    for (int nt = 0; nt < 9; ++nt) {
        const int ncol = nt * 16 + lrow;
        bf16x8 bfrag = *(const bf16x8*)&W1T[ncol * RB + kseg * 8];
        f32x4 acc = {0.f, 0.f, 0.f, 0.f};
        acc = __builtin_amdgcn_mfma_f32_16x16x32_bf16(afrag, bfrag, acc, 0, 0, 0);
        if (ncol < FD) {
            const float bias = b1[ncol];
            #pragma unroll
            for (int r = 0; r < 4; ++r)
                HT[kseg * 4 + r][ncol] = f2bf(silu_f(acc[r] + bias));
        }
    }
    // g rows 132..164: silu(evi @ We1 + be1)
    for (int idx = ln; idx < WE * 33; idx += 64) {
        int e = idx / 33, ii = idx - e * 33;
        float a = be1[ii];
        a = fmaf(evl[e * 3 + 0], We1[ii], a);
        a = fmaf(evl[e * 3 + 1], We1[33 + ii], a);
        a = fmaf(evl[e * 3 + 2], We1[66 + ii], a);
        HT[e][FD + ii] = f2bf(silu_f(a));
    }
    // zero-pad k 165..199
    for (int idx = ln; idx < WE * (KPAD - 165); idx += 64) {
        int e = idx / (KPAD - 165), kk = idx - e * (KPAD - 165);
        HT[e][165 + kk] = 0;
    }
    __syncthreads();   // 1-wave block: ~free, orders LDS

    // ---- main GEMM: fw[16][132] = Hext[16][165] @ Wcat[165][132] ----
    f32x4 acc[9];
    #pragma unroll
    for (int nt = 0; nt < 9; ++nt) acc[nt] = (f32x4){0.f, 0.f, 0.f, 0.f};
    {
        const unsigned short* hrow = &HT[lrow][0];
        #pragma unroll
        for (int kt = 0; kt < 6; ++kt) {
            bf16x8 af = *(const bf16x8*)&hrow[kt * 32 + kseg * 8];
            #pragma unroll
            for (int nt = 0; nt < 9; ++nt) {
                bf16x8 bfrag = *(const bf16x8*)&W2T[(nt * 16 + lrow) * KG + kt * 32 + kseg * 8];
                acc[nt] = __builtin_amdgcn_mfma_f32_16x16x32_bf16(af, bfrag, acc[nt], 0, 0, 0);
            }
        }
    }
    __syncthreads();   // HT reads done; safe to overwrite as FW

    #pragma unroll
    for (int nt = 0; nt < 9; ++nt) {
        const int ncol = nt * 16 + lrow;
        if (ncol < FD) {
            const float bias = b2[ncol] + be2[ncol];
            #pragma unroll
            for (int r = 0; r < 4; ++r)
                FW[(kseg * 4 + r) * FD + ncol] = acc[nt][r] + bias;
        }
    }
    __syncthreads();

    // ---- fused qk*fw head-sums -> alpha at sorted position ----
    // thread ln: edge eq = ln>>2, j-chunk jb = (ln&3)*33 .. +32
    {
        const int eq = ln >> 2;
        const int m  = ln & 3;
        const int jb = m * 33;
        const float* qp = qt + (size_t)rl[eq] * FD + jb;
        const float* kp = kt + (size_t)sl[eq] * FD + jb;
        const float* fp = &FW[eq * FD + jb];
        const int hlo   = jb / DH;
        const int split = (PATH == 0) ? 33 : (DH * (hlo + 1) - jb);
        float pa = 0.f, pb = 0.f;
        #pragma unroll
        for (int jj = 0; jj < 33; ++jj) {
            float f = fp[jj] * qp[jj] * kp[jj];
            if (jj < split) pa += f; else pb += f;
        }
        float nxt = __shfl_down(pa, 1);
        if (PATH == 0) {
            aout[(size_t)(p0 + eq) * 4 + m] = pa * cl[eq] * SC;
        } else {
            if (m < 3) {
                float a = ((m == 0) ? pa : pb) + nxt;
                aout[(size_t)(p0 + eq) * 4 + m] = a * cl[eq] * SC;
            }
        }
    }
}

// ---------------- fused edge kernel: both paths, wave-private 16-edge tile ---
__global__ __launch_bounds__(64, 4) void k_edge2(
    const float* __restrict__ rbf, const float* __restrict__ evi_s,
    const int* __restrict__ eid, const int* __restrict__ ss,
    const int* __restrict__ rs, const float* __restrict__ cut_s,
    const unsigned short* __restrict__ W1Ti, const float* __restrict__ b1i,
    const unsigned short* __restrict__ W2Ti, const float* __restrict__ b2i,
    const float* __restrict__ We1i, const float* __restrict__ be1i,
    const float* __restrict__ be2i,
    const float* __restrict__ qti, const float* __restrict__ kti,
    float* __restrict__ aoutI,
    const unsigned short* __restrict__ W1Te, const float* __restrict__ b1e,
    const unsigned short* __restrict__ W2Te, const float* __restrict__ b2e,
    const float* __restrict__ We1e, const float* __restrict__ be1e,
    const float* __restrict__ be2e,
    const float* __restrict__ qte, const float* __restrict__ kte,
    float* __restrict__ aoutE)
{
    // buffer: HT [16][200] bf16 (6.4KB) aliased with FW [16][132] f32 (8.45KB)
    __shared__ __align__(16) char lds_buf[WE * FD * 4];
    __shared__ float evl[WE * 3];
    __shared__ int   sl[WE];
    __shared__ int   rl[WE];
    __shared__ float cl[WE];

    typedef unsigned short (*HTp)[KPAD];
    HTp HT    = (HTp)lds_buf;
    float* FW = (float*)lds_buf;

    const int ln   = threadIdx.x;      // 0..63, one wave
    const int lrow = ln & 15;
    const int kseg = ln >> 4;
    const int p0   = blockIdx.x * WE;

    // A-frag: rbf row of this lane's edge (shared by both paths)
    const int eorg = eid[p0 + lrow];
    const float4 ra = *(const float4*)&rbf[(size_t)eorg * RB + kseg * 8];
    const float4 rb = *(const float4*)&rbf[(size_t)eorg * RB + kseg * 8 + 4];
    bf16x8 afrag;
    afrag[0] = (short)f2bf(ra.x); afrag[1] = (short)f2bf(ra.y);
    afrag[2] = (short)f2bf(ra.z); afrag[3] = (short)f2bf(ra.w);
    afrag[4] = (short)f2bf(rb.x); afrag[5] = (short)f2bf(rb.y);
    afrag[6] = (short)f2bf(rb.z); afrag[7] = (short)f2bf(rb.w);

    if (ln < WE) {
        sl[ln] = ss[p0 + ln];
        rl[ln] = rs[p0 + ln];
        cl[ln] = cut_s[p0 + ln];
    }
    if (ln < WE * 3) evl[ln] = evi_s[p0 * 3 + ln];
    __syncthreads();

    edge_path<0>(afrag, HT, FW, evl, sl, rl, cl,
                 W1Ti, b1i, W2Ti, b2i, We1i, be1i, be2i, qti, kti, aoutI,
                 ln, lrow, kseg, p0);
    __syncthreads();   // FW reads done before path 2 overwrites HT
    edge_path<1>(afrag, HT, FW, evl, sl, rl, cl,
                 W1Te, b1e, W2Te, b2e, We1e, be1e, be2e, qte, kte, aoutE,
                 ln, lrow, kseg, p0);
}

// ---------------- final node update: streamed CSR gather + Wint GEMM ---------
__global__ __launch_bounds__(256) void k_final(
    const float* __restrict__ xin, const float* __restrict__ evf,
    const float* __restrict__ vt, const float* __restrict__ sh,
    const float* __restrict__ alphaI, const float* __restrict__ alphaE,
    const int* __restrict__ roff, const int* __restrict__ eid,
    const int* __restrict__ ss,
    const float* __restrict__ Wint, const float* __restrict__ bint,
    float* __restrict__ out)
{
    __shared__ __align__(16) float catT[136][FNT];  // 15.2 KB
    __shared__ float aev[FNT][16];
    __shared__ float tacc[FNT][4];
    const int t = threadIdx.x;
    const int n0 = blockIdx.x * FNT;
    const int wv = t >> 6, ln = t & 63;

    const int h0 = ln / 33;
    const int h1 = (64 + ln) / 33;
    const int hm = (ln < 3) ? 0 : ((ln < 8) ? 1 : 2);
    for (int nl = wv; nl < FNT; nl += 4) {
        const int n = n0 + nl;
        float a0 = 0.f, a1 = 0.f, a2 = 0.f, dv = 0.f;
        if (n < NN) {
            const int pend = roff[n + 1];
            int p = roff[n];
            for (; p + 2 <= pend; p += 2) {
                const int sA = ss[p], sB = ss[p + 1];
                const int eA = eid[p], eB = eid[p + 1];
                const float* vA = vt + (size_t)sA * FD;
                const float* vB = vt + (size_t)sB * FD;
                const float aA0 = alphaI[(size_t)p * 4 + h0];
                const float aB0 = alphaI[(size_t)(p + 1) * 4 + h0];
                const float aA1 = alphaI[(size_t)p * 4 + h1];
                const float aB1 = alphaI[(size_t)(p + 1) * 4 + h1];
                a0 = fmaf(aA0, vA[ln], a0);      a0 = fmaf(aB0, vB[ln], a0);
                a1 = fmaf(aA1, vA[64 + ln], a1); a1 = fmaf(aB1, vB[64 + ln], a1);
                if (ln < 4) {
                    a2 = fmaf(alphaI[(size_t)p * 4 + 3], vA[128 + ln], a2);
                    a2 = fmaf(alphaI[(size_t)(p + 1) * 4 + 3], vB[128 + ln], a2);
                }
                if (ln < 15) {
                    dv = fmaf(alphaE[(size_t)p * 4 + hm], sh[(size_t)eA * EVD + ln], dv);
                    dv = fmaf(alphaE[(size_t)(p + 1) * 4 + hm], sh[(size_t)eB * EVD + ln], dv);
                }
            }
            for (; p < pend; ++p) {
                const int sA = ss[p];
                const int eA = eid[p];
                const float* vA = vt + (size_t)sA * FD;
                a0 = fmaf(alphaI[(size_t)p * 4 + h0], vA[ln], a0);
                a1 = fmaf(alphaI[(size_t)p * 4 + h1], vA[64 + ln], a1);
                if (ln < 4)  a2 = fmaf(alphaI[(size_t)p * 4 + 3], vA[128 + ln], a2);
                if (ln < 15) dv = fmaf(alphaE[(size_t)p * 4 + hm], sh[(size_t)eA * EVD + ln], dv);
            }
            catT[ln][nl]      = xin[n * FD + ln]      + a0;
            catT[64 + ln][nl] = xin[n * FD + 64 + ln] + a1;
            if (ln < 4)  catT[128 + ln][nl] = xin[n * FD + 128 + ln] + a2;
            if (ln < 15) aev[nl][ln] = evf[n * EVD + ln] + dv;
        } else {
            catT[ln][nl] = 0.f; catT[64 + ln][nl] = 0.f;
            if (ln < 4)  catT[128 + ln][nl] = 0.f;
            if (ln < 15) aev[nl][ln] = 0.f;
        }
    }
    if (t < FNT) catT[135][t] = 0.0f;
    __syncthreads();
    if (t < FNT * 3) {
        int nl = t / 3, k = t - nl * 3;
        int lo = (k == 0) ? 0 : ((k == 1) ? 3 : 8);
        int hi = (k == 0) ? 3 : ((k == 1) ? 8 : 15);
        float s = 0.f;
        for (int m = lo; m < hi; ++m) { float v = aev[nl][m]; s = fmaf(v, v, s); }
        catT[FD + k][nl] = s;
    }
    __syncthreads();

    const int q = t % 34, g = t / 34;
    const int jb = q * 4, nb = g * 4;
    const bool act = (g < 7);
    float acc[4][4] = {};
    if (act) {
        #pragma unroll 5
        for (int c = 0; c < 135; ++c) {
            const float* wr = Wint + c * 135 + jb;
            const float w0 = wr[0];
            const float w1 = wr[1];
            const float w2 = wr[2];
            const float w3 = (jb + 3 < 135) ? wr[3] : 0.f;
            const float4 x = *(const float4*)&catT[c][nb];
            const float xs[4] = {x.x, x.y, x.z, x.w};
            #pragma unroll
            for (int r = 0; r < 4; ++r) {
                acc[r][0] = fmaf(w0, xs[r], acc[r][0]);
                acc[r][1] = fmaf(w1, xs[r], acc[r][1]);
                acc[r][2] = fmaf(w2, xs[r], acc[r][2]);
                acc[r][3] = fmaf(w3, xs[r], acc[r][3]);
            }
        }
        #pragma unroll
        for (int c = 0; c < 4; ++c) {
            int j = jb + c;
            if (j >= 135) break;
            float bj = bint[j];
            #pragma unroll
            for (int r = 0; r < 4; ++r) {
                int n = n0 + nb + r;
                if (n >= NN) continue;
                float a = acc[r][c] + bj;
                if (j < FD) out[n * FD + j] = catT[j][nb + r] + a;
                else        tacc[nb + r][j - FD] = a;
            }
        }
    }
    __syncthreads();
    for (int idx = t; idx < FNT * EVD; idx += 256) {
        int nl = idx / EVD, m = idx - nl * EVD;
        int n = n0 + nl;
        if (n >= NN) continue;
        int hd = (m < 3) ? 0 : ((m < 8) ? 1 : 2);
        out[NN * FD + n * EVD + m] = aev[nl][m] * (1.0f + tacc[nl][hd]);
    }
}

extern "C" void kernel_launch(void* const* d_in, const int* in_sizes, int n_in,
                              void* d_out, int out_size, void* d_ws, size_t ws_size,
                              hipStream_t stream)
{
    (void)in_sizes; (void)n_in; (void)out_size; (void)ws_size;
    const float* xin  = (const float*)d_in[0];
    const float* evf  = (const float*)d_in[1];
    const float* rbf  = (const float*)d_in[2];
    const int*   snd  = (const int*)d_in[3];
    const int*   rcv  = (const int*)d_in[4];
    const float* sh   = (const float*)d_in[5];
    const float* cut  = (const float*)d_in[6];
    const float* Wint = (const float*)d_in[28];
    const float* bint = (const float*)d_in[29];

    float* ws     = (float*)d_ws;
    float* qinv   = ws;                        // NN*FD
    float* kinv   = qinv   + NN * FD;
    float* vinv   = kinv   + NN * FD;
    float* qev    = vinv   + NN * FD;
    float* kev    = qev    + NN * FD;
    float* alphaI = kev    + NN * FD;          // NE*4
    float* alphaE = alphaI + NE * 4;           // NE*4
    float* evi_s  = alphaE + NE * 4;           // NE*3
    float* cut_s  = evi_s  + NE * 3;           // NE
    int*   iwork  = (int*)(cut_s + NE);
    int*   roff   = iwork;                     // NN+1
    int*   cnt_cursor = roff + (NN + 1);       // NN
    int*   eid    = cnt_cursor + NN;           // NE
    int*   ss     = eid + NE;                  // NE
    int*   rs     = ss + NE;                   // NE
    float* wtail  = (float*)(iwork + 640004);  // pad: 16B alignment

    unsigned short* W2Tfi = (unsigned short*)wtail;        // 27648 bf16
    unsigned short* W2Tfe = W2Tfi + NP * KG;               // 27648
    unsigned short* W1Tfi = W2Tfe + NP * KG;               // 4608
    unsigned short* W1Tfe = W1Tfi + NP * RB;               // 4608
    float* WqP = (float*)(W1Tfe + NP * RB);                // 4752 f32 each
    float* WkP = WqP + 4 * 33 * 36;
    float* WvP = WkP + 4 * 33 * 36;

    // ---- CSR build + sorted streams ----
    hipMemsetAsync(cnt_cursor, 0, (size_t)NN * sizeof(int), stream);
    k_hist<<<(NE + 255) / 256, 256, 0, stream>>>(rcv, cnt_cursor);
    k_scan<<<1, 1024, 0, stream>>>(cnt_cursor, roff);
    k_fill<<<(NE + 255) / 256, 256, 0, stream>>>(rcv, cnt_cursor, eid);
    k_eprep<<<(NE + 255) / 256, 256, 0, stream>>>(evf, snd, rcv, cut, eid,
                                                  evi_s, cut_s, ss, rs);

    k_prep<<<64, 256, 0, stream>>>(
        (const float*)d_in[7], (const float*)d_in[8], (const float*)d_in[9],
        (const float*)d_in[12], (const float*)d_in[14], (const float*)d_in[18],
        (const float*)d_in[20], (const float*)d_in[22], (const float*)d_in[26],
        W1Tfi, W1Tfe, W2Tfi, W2Tfe, WqP, WkP, WvP);

    k_proj<<<(NN + PNT - 1) / PNT, 256, 0, stream>>>(
        xin, WqP, WkP, WvP,
        (const float*)d_in[10], (const float*)d_in[11],
        qinv, kinv, vinv, qev, kev);

    k_edge2<<<NE / WE, 64, 0, stream>>>(rbf, evi_s, eid, ss, rs, cut_s,
        W1Tfi, (const float*)d_in[13], W2Tfi, (const float*)d_in[15],
        (const float*)d_in[16], (const float*)d_in[17], (const float*)d_in[19],
        qinv, kinv, alphaI,
        W1Tfe, (const float*)d_in[21], W2Tfe, (const float*)d_in[23],
        (const float*)d_in[24], (const float*)d_in[25], (const float*)d_in[27],
        qev, kev, alphaE);

    k_final<<<(NN + FNT - 1) / FNT, 256, 0, stream>>>(
        xin, evf, vinv, sh, alphaI, alphaE, roff, eid, ss,
        Wint, bint, (float*)d_out);
}